// Round 4
// baseline (1510.711 us; speedup 1.0000x reference)
//
#include <hip/hip_runtime.h>

#define BH_ 32
#define S_ 2048
#define D_ 64
#define NW 8
#define SCALER_ 0.125f

typedef float f32x4 __attribute__((ext_vector_type(4)));
typedef short bf16x8 __attribute__((ext_vector_type(8)));

__device__ __forceinline__ unsigned short f2bf(float x){
  unsigned int u = __builtin_bit_cast(unsigned int, x);
  u += 0x7fffu + ((u >> 16) & 1u);
  return (unsigned short)(u >> 16);
}

__device__ __forceinline__ float bf2f(unsigned short u){
  return __builtin_bit_cast(float, (unsigned int)u << 16);
}

__device__ __forceinline__ bf16x8 pack8(float4 a, float4 b){
  bf16x8 r;
  r[0]=(short)f2bf(a.x); r[1]=(short)f2bf(a.y); r[2]=(short)f2bf(a.z); r[3]=(short)f2bf(a.w);
  r[4]=(short)f2bf(b.x); r[5]=(short)f2bf(b.y); r[6]=(short)f2bf(b.z); r[7]=(short)f2bf(b.w);
  return r;
}

// LDS layout (46656 B total):
//   vt    : [64][264] bf16 (33792 B)  V-chunk transposed
//   ptile : [NW][16][40] bf16 (10240 B) per-wave chunk P tile
//   maskb : 2048 B  per-batch key mask
//   rsf   : [NW][16] f32, invf: [16] f32
//   ctxb  : [128][66] f32 = 33792 B aliased over vt ONLY (never over ptile!)
__global__ __launch_bounds__(512, 6) void sdpa_kernel(
    const float* __restrict__ Q, const float* __restrict__ K,
    const float* __restrict__ V, const int* __restrict__ M,
    float* __restrict__ out)
{
  __shared__ __align__(16) unsigned char smem[46656];
  unsigned short* vt    = (unsigned short*)smem;
  unsigned int*   vtw   = (unsigned int*)smem;
  short*          ptile = (short*)(smem + 33792);
  unsigned char*  maskb = smem + 44032;
  float* rsf  = (float*)(smem + 46080);
  float* invf = (float*)(smem + 46592);

  const int t = threadIdx.x;
  const int w = t >> 6;
  const int l = t & 63;
  const int m = l & 15;          // MFMA col-lane / A-row
  const int quad = l >> 4;       // MFMA quad

  // XCD-aware swizzle: each XCD gets 512 contiguous logical blocks so its
  // resident blocks share one bh; K/V stay in that XCD's L2.
  const int wg = ((blockIdx.x & 7) << 9) | (blockIdx.x >> 3);
  const int bh = wg >> 7;
  const int q0 = (wg & 127) << 4;
  const int b  = bh >> 4;        // H = 16

  const float* Qp = Q + ((size_t)bh*S_ + q0)*D_;
  const float* Kp = K + (size_t)bh*S_*D_;
  const float* Vp = V + (size_t)bh*S_*D_;
  float* ctx_out = out + ((size_t)bh*S_ + q0)*D_;
  float* P_out   = out + (size_t)BH_*S_*D_ + ((size_t)bh*S_ + q0)*(size_t)S_;

  // stage mask row (per batch) to LDS (int32 -> 1 byte/key)
  {
    const int4 mi = ((const int4*)(M + (size_t)b*S_))[t];
    unsigned int pk = (mi.x ? 1u : 0u) | ((mi.y ? 1u : 0u) << 8)
                    | ((mi.z ? 1u : 0u) << 16) | ((mi.w ? 1u : 0u) << 24);
    ((unsigned int*)maskb)[t] = pk;
  }

  // Q fragments: A[m][k=quad*8+j], frag0 = d 0..31, frag1 = d 32..63
  bf16x8 qf0, qf1;
  {
    const float* qrow = Qp + m*D_ + quad*8;
    qf0 = pack8(*(const float4*)(qrow),      *(const float4*)(qrow + 4));
    qf1 = pack8(*(const float4*)(qrow + 32), *(const float4*)(qrow + 36));
  }
  __syncthreads();

  // ---------- pass 1: softmax row sums (2-stage software pipeline) ----------
  float rsum[4] = {0.f, 0.f, 0.f, 0.f};
  float4 a0, a1, a2, a3;
  {
    const float* kr = Kp + (size_t)((w << 4) + m)*D_ + quad*8;
    a0 = *(const float4*)(kr);      a1 = *(const float4*)(kr + 4);
    a2 = *(const float4*)(kr + 32); a3 = *(const float4*)(kr + 36);
  }
  for (int tile = w; tile < 128; tile += NW) {
    const float4 b0 = a0, b1 = a1, b2 = a2, b3 = a3;
    if (tile + NW < 128) {
      const float* kr = Kp + (size_t)(((tile + NW) << 4) + m)*D_ + quad*8;
      a0 = *(const float4*)(kr);      a1 = *(const float4*)(kr + 4);
      a2 = *(const float4*)(kr + 32); a3 = *(const float4*)(kr + 36);
    }
    bf16x8 kf0 = pack8(b0, b1);
    bf16x8 kf1 = pack8(b2, b3);
    f32x4 c = {0.f, 0.f, 0.f, 0.f};
    c = __builtin_amdgcn_mfma_f32_16x16x32_bf16(qf0, kf0, c, 0, 0, 0);
    c = __builtin_amdgcn_mfma_f32_16x16x32_bf16(qf1, kf1, c, 0, 0, 0);
    const bool mskd = maskb[(tile << 4) + m] != 0;
    #pragma unroll
    for (int r = 0; r < 4; r++) {
      float e = mskd ? 0.f : __expf(c[r] * SCALER_);
      rsum[r] += e;
    }
  }
  #pragma unroll
  for (int r = 0; r < 4; r++) {
    float v = rsum[r];
    v += __shfl_xor(v, 1); v += __shfl_xor(v, 2);
    v += __shfl_xor(v, 4); v += __shfl_xor(v, 8);
    if (m == 0) rsf[w*16 + quad*4 + r] = v;
  }
  __syncthreads();
  if (t < 16) {
    float s = 0.f;
    #pragma unroll
    for (int wv = 0; wv < NW; wv++) s += rsf[wv*16 + t];
    invf[t] = 1.0f / s;
  }
  __syncthreads();
  float invq[4];
  #pragma unroll
  for (int r = 0; r < 4; r++) invq[r] = invf[quad*4 + r];

  // ---------- pass 2: recompute scores, PV MFMA, per-wave nt P store ----------
  f32x4 acc[4];
  #pragma unroll
  for (int n = 0; n < 4; n++) acc[n] = (f32x4){0.f, 0.f, 0.f, 0.f};

  const int gg = (t >> 4) & 15;   // d-group for V staging
  const int ph = t >> 8;          // 0..1
  const int pl = t & 15;          // pair-lane: spreads LDS banks

  // per-wave P store mapping: 16 rows x 32 cols per wave
  const int prow2 = l >> 2;        // 0..15
  const int pcs   = (l & 3) << 3;  // 0,8,16,24

  // V prefetch registers (issue-early / write-late, T14)
  float4 pva0, pva1, pva2, pva3, pvb0, pvb1, pvb2, pvb3;
  {
    const int p0 = pl + 16*(0 + ph), p1 = pl + 16*(2 + ph);
    const int p2 = pl + 16*(4 + ph), p3 = pl + 16*(6 + ph);
    pva0 = *(const float4*)(Vp + (size_t)(2*p0    )*D_ + 4*gg);
    pvb0 = *(const float4*)(Vp + (size_t)(2*p0 + 1)*D_ + 4*gg);
    pva1 = *(const float4*)(Vp + (size_t)(2*p1    )*D_ + 4*gg);
    pvb1 = *(const float4*)(Vp + (size_t)(2*p1 + 1)*D_ + 4*gg);
    pva2 = *(const float4*)(Vp + (size_t)(2*p2    )*D_ + 4*gg);
    pvb2 = *(const float4*)(Vp + (size_t)(2*p2 + 1)*D_ + 4*gg);
    pva3 = *(const float4*)(Vp + (size_t)(2*p3    )*D_ + 4*gg);
    pvb3 = *(const float4*)(Vp + (size_t)(2*p3 + 1)*D_ + 4*gg);
  }

  for (int c = 0; c < 8; ++c) {
    const int kc = c << 8;
    // A: all waves done reading vt from previous chunk. RAW barrier (no vmcnt
    // drain) — each wave's own lgkm deps were already satisfied by MFMA use.
    __builtin_amdgcn_s_barrier();

    // write prefetched V regs to vt (compiler inserts vmcnt waits on reg use)
    {
      const float* vaf; const float* vbf; int p;
      #define STORE_PAIR(A,B,I) \
        p = pl + 16*(2*(I) + ph); vaf = (const float*)&(A); vbf = (const float*)&(B); \
        _Pragma("unroll") \
        for (int j = 0; j < 4; j++) { \
          unsigned int pk = (unsigned int)f2bf(vaf[j]) | ((unsigned int)f2bf(vbf[j]) << 16); \
          vtw[(4*gg + j)*132 + p] = pk; \
        }
      STORE_PAIR(pva0, pvb0, 0)
      STORE_PAIR(pva1, pvb1, 1)
      STORE_PAIR(pva2, pvb2, 2)
      STORE_PAIR(pva3, pvb3, 3)
      #undef STORE_PAIR
    }

    // issue NEXT chunk's V loads now — they stay in flight across barrier B
    if (c < 7) {
      const float* Vn = Vp + (size_t)(kc + 256)*D_;
      const int p0 = pl + 16*(0 + ph), p1 = pl + 16*(2 + ph);
      const int p2 = pl + 16*(4 + ph), p3 = pl + 16*(6 + ph);
      pva0 = *(const float4*)(Vn + (size_t)(2*p0    )*D_ + 4*gg);
      pvb0 = *(const float4*)(Vn + (size_t)(2*p0 + 1)*D_ + 4*gg);
      pva1 = *(const float4*)(Vn + (size_t)(2*p1    )*D_ + 4*gg);
      pvb1 = *(const float4*)(Vn + (size_t)(2*p1 + 1)*D_ + 4*gg);
      pva2 = *(const float4*)(Vn + (size_t)(2*p2    )*D_ + 4*gg);
      pvb2 = *(const float4*)(Vn + (size_t)(2*p2 + 1)*D_ + 4*gg);
      pva3 = *(const float4*)(Vn + (size_t)(2*p3    )*D_ + 4*gg);
      pvb3 = *(const float4*)(Vn + (size_t)(2*p3 + 1)*D_ + 4*gg);
    }

    // make ds_writes visible, then release waves into compute
    asm volatile("s_waitcnt lgkmcnt(0)" ::: "memory");
    __builtin_amdgcn_sched_barrier(0);
    __builtin_amdgcn_s_barrier();     // B: vt ready (V(c+1) loads still in flight)

    // this wave's 32 keys of the chunk -> P values into its own ptile
    const int kbase = kc + w*32;
    short* pt = ptile + w*640;
    #pragma unroll
    for (int s2 = 0; s2 < 2; s2++) {
      const int k0 = kbase + (s2 << 4);
      const float* krow = Kp + (size_t)(k0 + m)*D_ + quad*8;
      bf16x8 kf0 = pack8(*(const float4*)(krow),      *(const float4*)(krow + 4));
      bf16x8 kf1 = pack8(*(const float4*)(krow + 32), *(const float4*)(krow + 36));
      f32x4 sc = {0.f, 0.f, 0.f, 0.f};
      sc = __builtin_amdgcn_mfma_f32_16x16x32_bf16(qf0, kf0, sc, 0, 0, 0);
      sc = __builtin_amdgcn_mfma_f32_16x16x32_bf16(qf1, kf1, sc, 0, 0, 0);
      const bool mskd = maskb[k0 + m] != 0;
      #pragma unroll
      for (int r = 0; r < 4; r++) {
        float e  = mskd ? 0.f : __expf(sc[r] * SCALER_);
        float pv = e * invq[r];
        const int row = quad*4 + r;       // C/D layout: row=(lane>>4)*4+reg, col=lane&15
        pt[row*40 + (s2 << 4) + m] = (short)f2bf(pv);
      }
    }
    // own-wave lgkm dependency only — no barrier needed before reading pt back

    // per-wave nt P store: lane l -> row prow2, cols kbase+pcs..+7 (2x f32x4)
    {
      const bf16x8 p8 = *(const bf16x8*)(pt + prow2*40 + pcs);
      f32x4 o0, o1;
      o0[0] = bf2f((unsigned short)p8[0]); o0[1] = bf2f((unsigned short)p8[1]);
      o0[2] = bf2f((unsigned short)p8[2]); o0[3] = bf2f((unsigned short)p8[3]);
      o1[0] = bf2f((unsigned short)p8[4]); o1[1] = bf2f((unsigned short)p8[5]);
      o1[2] = bf2f((unsigned short)p8[6]); o1[3] = bf2f((unsigned short)p8[7]);
      float* dst = P_out + (size_t)prow2*S_ + kbase + pcs;
      __builtin_nontemporal_store(o0, (f32x4*)(dst));
      __builtin_nontemporal_store(o1, (f32x4*)(dst + 4));
    }

    // P (A-layout) from own pt, V^T (B-layout) from vt, 4 d-tiles
    bf16x8 af = *(const bf16x8*)(pt + m*40 + quad*8);
    #pragma unroll
    for (int n = 0; n < 4; n++) {
      bf16x8 bfv = *(const bf16x8*)(vt + (size_t)(n*16 + m)*264 + (w*32 + quad*8));
      acc[n] = __builtin_amdgcn_mfma_f32_16x16x32_bf16(af, bfv, acc[n], 0, 0, 0);
    }
  }

  // ---------- epilogue: cross-wave context reduction (ctxb aliases vt ONLY) ----------
  __syncthreads();                 // full drain: all vt/ptile reads done
  float* ctxb = (float*)smem;      // [128][66] f32 = 33792 B, inside vt region
  #pragma unroll
  for (int n = 0; n < 4; n++) {
    #pragma unroll
    for (int r = 0; r < 4; r++) {
      ctxb[(size_t)(w*16 + quad*4 + r)*66 + n*16 + m] = acc[n][r];
    }
  }
  __syncthreads();
  if (t < 256) {
    const int e4  = t << 2;
    const int row = e4 >> 6;
    const int col = e4 & 63;
    float s0 = 0.f, s1 = 0.f, s2 = 0.f, s3 = 0.f;
    #pragma unroll
    for (int wv = 0; wv < NW; wv++) {
      const float* p = ctxb + (size_t)(wv*16 + row)*66 + col;
      s0 += p[0]; s1 += p[1]; s2 += p[2]; s3 += p[3];
    }
    f32x4 o; o[0] = s0; o[1] = s1; o[2] = s2; o[3] = s3;
    __builtin_nontemporal_store(o, (f32x4*)(ctx_out + row*D_ + col));
  }
}

extern "C" void kernel_launch(void* const* d_in, const int* in_sizes, int n_in,
                              void* d_out, int out_size, void* d_ws, size_t ws_size,
                              hipStream_t stream) {
  const float* Q = (const float*)d_in[0];
  const float* K = (const float*)d_in[1];
  const float* V = (const float*)d_in[2];
  const int* M = (const int*)d_in[3];
  float* out = (float*)d_out;
  sdpa_kernel<<<dim3(4096), dim3(512), 0, stream>>>(Q, K, V, M, out);
}

// Round 7
// 1500.792 us; speedup vs baseline: 1.0066x; 1.0066x over previous
//
#include <hip/hip_runtime.h>

#define BH_ 32
#define S_ 2048
#define D_ 64
#define NW 8
#define SCALER_ 0.125f

typedef float f32x4 __attribute__((ext_vector_type(4)));
typedef short bf16x8 __attribute__((ext_vector_type(8)));

__device__ __forceinline__ unsigned short f2bf(float x){
  unsigned int u = __builtin_bit_cast(unsigned int, x);
  u += 0x7fffu + ((u >> 16) & 1u);
  return (unsigned short)(u >> 16);
}

__device__ __forceinline__ float bf2f(unsigned short u){
  return __builtin_bit_cast(float, (unsigned int)u << 16);
}

__device__ __forceinline__ bf16x8 pack8(float4 a, float4 b){
  bf16x8 r;
  r[0]=(short)f2bf(a.x); r[1]=(short)f2bf(a.y); r[2]=(short)f2bf(a.z); r[3]=(short)f2bf(a.w);
  r[4]=(short)f2bf(b.x); r[5]=(short)f2bf(b.y); r[6]=(short)f2bf(b.z); r[7]=(short)f2bf(b.w);
  return r;
}

// LDS layout (46656 B total):
//   vt    : [64][264] bf16 (33792 B)  V-chunk transposed
//   ptile : [NW][16][40] bf16 (10240 B) per-wave chunk P tile
//   maskb : 2048 B  per-batch key mask
//   rsf   : [NW][16] f32, invf: [16] f32
//   ctxb  : [128][66] f32 = 33792 B aliased over vt ONLY (never over ptile!)
__global__ __launch_bounds__(512, 6) void sdpa_kernel(
    const float* __restrict__ Q, const float* __restrict__ K,
    const float* __restrict__ V, const int* __restrict__ M,
    float* __restrict__ out)
{
  __shared__ __align__(16) unsigned char smem[46656];
  unsigned short* vt    = (unsigned short*)smem;
  unsigned int*   vtw   = (unsigned int*)smem;
  short*          ptile = (short*)(smem + 33792);
  unsigned char*  maskb = smem + 44032;
  float* rsf  = (float*)(smem + 46080);
  float* invf = (float*)(smem + 46592);

  const int t = threadIdx.x;
  const int w = t >> 6;
  const int l = t & 63;
  const int m = l & 15;          // MFMA col-lane / A-row
  const int quad = l >> 4;       // MFMA quad

  // XCD-aware swizzle: each XCD gets 512 contiguous logical blocks so its
  // resident blocks share one bh; K/V stay in that XCD's L2.
  const int wg = ((blockIdx.x & 7) << 9) | (blockIdx.x >> 3);
  const int bh = wg >> 7;
  const int q0 = (wg & 127) << 4;
  const int b  = bh >> 4;        // H = 16

  const float* Qp = Q + ((size_t)bh*S_ + q0)*D_;
  const float* Kp = K + (size_t)bh*S_*D_;
  const float* Vp = V + (size_t)bh*S_*D_;
  float* ctx_out = out + ((size_t)bh*S_ + q0)*D_;
  float* P_out   = out + (size_t)BH_*S_*D_ + ((size_t)bh*S_ + q0)*(size_t)S_;

  // stage mask row (per batch) to LDS (int32 -> 1 byte/key)
  {
    const int4 mi = ((const int4*)(M + (size_t)b*S_))[t];
    unsigned int pk = (mi.x ? 1u : 0u) | ((mi.y ? 1u : 0u) << 8)
                    | ((mi.z ? 1u : 0u) << 16) | ((mi.w ? 1u : 0u) << 24);
    ((unsigned int*)maskb)[t] = pk;
  }

  // Q fragments: A[m][k=quad*8+j], frag0 = d 0..31, frag1 = d 32..63
  bf16x8 qf0, qf1;
  {
    const float* qrow = Qp + m*D_ + quad*8;
    qf0 = pack8(*(const float4*)(qrow),      *(const float4*)(qrow + 4));
    qf1 = pack8(*(const float4*)(qrow + 32), *(const float4*)(qrow + 36));
  }
  __syncthreads();

  // ---------- pass 1: softmax row sums (2-stage software pipeline) ----------
  float rsum[4] = {0.f, 0.f, 0.f, 0.f};
  float4 a0, a1, a2, a3;
  {
    const float* kr = Kp + (size_t)((w << 4) + m)*D_ + quad*8;
    a0 = *(const float4*)(kr);      a1 = *(const float4*)(kr + 4);
    a2 = *(const float4*)(kr + 32); a3 = *(const float4*)(kr + 36);
  }
  for (int tile = w; tile < 128; tile += NW) {
    const float4 b0 = a0, b1 = a1, b2 = a2, b3 = a3;
    if (tile + NW < 128) {
      const float* kr = Kp + (size_t)(((tile + NW) << 4) + m)*D_ + quad*8;
      a0 = *(const float4*)(kr);      a1 = *(const float4*)(kr + 4);
      a2 = *(const float4*)(kr + 32); a3 = *(const float4*)(kr + 36);
    }
    bf16x8 kf0 = pack8(b0, b1);
    bf16x8 kf1 = pack8(b2, b3);
    f32x4 c = {0.f, 0.f, 0.f, 0.f};
    c = __builtin_amdgcn_mfma_f32_16x16x32_bf16(qf0, kf0, c, 0, 0, 0);
    c = __builtin_amdgcn_mfma_f32_16x16x32_bf16(qf1, kf1, c, 0, 0, 0);
    const bool mskd = maskb[(tile << 4) + m] != 0;
    #pragma unroll
    for (int r = 0; r < 4; r++) {
      float e = mskd ? 0.f : __expf(c[r] * SCALER_);
      rsum[r] += e;
    }
  }
  #pragma unroll
  for (int r = 0; r < 4; r++) {
    float v = rsum[r];
    v += __shfl_xor(v, 1); v += __shfl_xor(v, 2);
    v += __shfl_xor(v, 4); v += __shfl_xor(v, 8);
    if (m == 0) rsf[w*16 + quad*4 + r] = v;
  }
  __syncthreads();
  if (t < 16) {
    float s = 0.f;
    #pragma unroll
    for (int wv = 0; wv < NW; wv++) s += rsf[wv*16 + t];
    invf[t] = 1.0f / s;
  }
  __syncthreads();
  float invq[4];
  #pragma unroll
  for (int r = 0; r < 4; r++) invq[r] = invf[quad*4 + r];

  // ---------- pass 2: recompute scores, PV MFMA, per-wave P store ----------
  f32x4 acc[4];
  #pragma unroll
  for (int n = 0; n < 4; n++) acc[n] = (f32x4){0.f, 0.f, 0.f, 0.f};

  const int gg = (t >> 4) & 15;   // d-group for V staging
  const int ph = t >> 8;          // 0..1
  const int pl = t & 15;          // pair-lane: spreads LDS banks

  // per-wave P store mapping: 16 rows x 32 cols per wave
  const int prow2 = l >> 2;        // 0..15
  const int pcs   = (l & 3) << 3;  // 0,8,16,24

  // V prefetch registers (issue-early / write-late, T14)
  float4 pva0, pva1, pva2, pva3, pvb0, pvb1, pvb2, pvb3;
  {
    const int p0 = pl + 16*(0 + ph), p1 = pl + 16*(2 + ph);
    const int p2 = pl + 16*(4 + ph), p3 = pl + 16*(6 + ph);
    pva0 = *(const float4*)(Vp + (size_t)(2*p0    )*D_ + 4*gg);
    pvb0 = *(const float4*)(Vp + (size_t)(2*p0 + 1)*D_ + 4*gg);
    pva1 = *(const float4*)(Vp + (size_t)(2*p1    )*D_ + 4*gg);
    pvb1 = *(const float4*)(Vp + (size_t)(2*p1 + 1)*D_ + 4*gg);
    pva2 = *(const float4*)(Vp + (size_t)(2*p2    )*D_ + 4*gg);
    pvb2 = *(const float4*)(Vp + (size_t)(2*p2 + 1)*D_ + 4*gg);
    pva3 = *(const float4*)(Vp + (size_t)(2*p3    )*D_ + 4*gg);
    pvb3 = *(const float4*)(Vp + (size_t)(2*p3 + 1)*D_ + 4*gg);
  }

  for (int c = 0; c < 8; ++c) {
    const int kc = c << 8;
    // A: all waves done reading vt from previous chunk. RAW barrier (no vmcnt
    // drain) — each wave's own lgkm deps were already satisfied by MFMA use.
    __builtin_amdgcn_s_barrier();

    // write prefetched V regs to vt (compiler inserts vmcnt waits on reg use)
    {
      const float* vaf; const float* vbf; int p;
      #define STORE_PAIR(A,B,I) \
        p = pl + 16*(2*(I) + ph); vaf = (const float*)&(A); vbf = (const float*)&(B); \
        _Pragma("unroll") \
        for (int j = 0; j < 4; j++) { \
          unsigned int pk = (unsigned int)f2bf(vaf[j]) | ((unsigned int)f2bf(vbf[j]) << 16); \
          vtw[(4*gg + j)*132 + p] = pk; \
        }
      STORE_PAIR(pva0, pvb0, 0)
      STORE_PAIR(pva1, pvb1, 1)
      STORE_PAIR(pva2, pvb2, 2)
      STORE_PAIR(pva3, pvb3, 3)
      #undef STORE_PAIR
    }

    // issue NEXT chunk's V loads now — they stay in flight across barrier B
    if (c < 7) {
      const float* Vn = Vp + (size_t)(kc + 256)*D_;
      const int p0 = pl + 16*(0 + ph), p1 = pl + 16*(2 + ph);
      const int p2 = pl + 16*(4 + ph), p3 = pl + 16*(6 + ph);
      pva0 = *(const float4*)(Vn + (size_t)(2*p0    )*D_ + 4*gg);
      pvb0 = *(const float4*)(Vn + (size_t)(2*p0 + 1)*D_ + 4*gg);
      pva1 = *(const float4*)(Vn + (size_t)(2*p1    )*D_ + 4*gg);
      pvb1 = *(const float4*)(Vn + (size_t)(2*p1 + 1)*D_ + 4*gg);
      pva2 = *(const float4*)(Vn + (size_t)(2*p2    )*D_ + 4*gg);
      pvb2 = *(const float4*)(Vn + (size_t)(2*p2 + 1)*D_ + 4*gg);
      pva3 = *(const float4*)(Vn + (size_t)(2*p3    )*D_ + 4*gg);
      pvb3 = *(const float4*)(Vn + (size_t)(2*p3 + 1)*D_ + 4*gg);
    }

    // make ds_writes visible, then release waves into compute
    asm volatile("s_waitcnt lgkmcnt(0)" ::: "memory");
    __builtin_amdgcn_sched_barrier(0);
    __builtin_amdgcn_s_barrier();     // B: vt ready (V(c+1) loads still in flight)

    // this wave's 32 keys of the chunk -> P values into its own ptile
    const int kbase = kc + w*32;
    short* pt = ptile + w*640;
    #pragma unroll
    for (int s2 = 0; s2 < 2; s2++) {
      const int k0 = kbase + (s2 << 4);
      const float* krow = Kp + (size_t)(k0 + m)*D_ + quad*8;
      bf16x8 kf0 = pack8(*(const float4*)(krow),      *(const float4*)(krow + 4));
      bf16x8 kf1 = pack8(*(const float4*)(krow + 32), *(const float4*)(krow + 36));
      f32x4 sc = {0.f, 0.f, 0.f, 0.f};
      sc = __builtin_amdgcn_mfma_f32_16x16x32_bf16(qf0, kf0, sc, 0, 0, 0);
      sc = __builtin_amdgcn_mfma_f32_16x16x32_bf16(qf1, kf1, sc, 0, 0, 0);
      const bool mskd = maskb[k0 + m] != 0;
      #pragma unroll
      for (int r = 0; r < 4; r++) {
        float e  = mskd ? 0.f : __expf(sc[r] * SCALER_);
        float pv = e * invq[r];
        const int row = quad*4 + r;       // C/D layout: row=(lane>>4)*4+reg, col=lane&15
        pt[row*40 + (s2 << 4) + m] = (short)f2bf(pv);
      }
    }
    // own-wave lgkm dependency only — no barrier needed before reading pt back

    // per-wave P store: lane l -> row prow2, cols kbase+pcs..+7 (2x f32x4)
    {
      const bf16x8 p8 = *(const bf16x8*)(pt + prow2*40 + pcs);
      f32x4 o0, o1;
      o0[0] = bf2f((unsigned short)p8[0]); o0[1] = bf2f((unsigned short)p8[1]);
      o0[2] = bf2f((unsigned short)p8[2]); o0[3] = bf2f((unsigned short)p8[3]);
      o1[0] = bf2f((unsigned short)p8[4]); o1[1] = bf2f((unsigned short)p8[5]);
      o1[2] = bf2f((unsigned short)p8[6]); o1[3] = bf2f((unsigned short)p8[7]);
      float* dst = P_out + (size_t)prow2*S_ + kbase + pcs;
      *(f32x4*)(dst)     = o0;
      *(f32x4*)(dst + 4) = o1;
    }

    // P (A-layout) from own pt, V^T (B-layout) from vt, 4 d-tiles
    bf16x8 af = *(const bf16x8*)(pt + m*40 + quad*8);
    #pragma unroll
    for (int n = 0; n < 4; n++) {
      bf16x8 bfv = *(const bf16x8*)(vt + (size_t)(n*16 + m)*264 + (w*32 + quad*8));
      acc[n] = __builtin_amdgcn_mfma_f32_16x16x32_bf16(af, bfv, acc[n], 0, 0, 0);
    }
  }

  // ---------- epilogue: cross-wave context reduction (ctxb aliases vt ONLY) ----------
  __syncthreads();                 // full drain: all vt/ptile reads done
  float* ctxb = (float*)smem;      // [128][66] f32 = 33792 B, inside vt region
  #pragma unroll
  for (int n = 0; n < 4; n++) {
    #pragma unroll
    for (int r = 0; r < 4; r++) {
      ctxb[(size_t)(w*16 + quad*4 + r)*66 + n*16 + m] = acc[n][r];
    }
  }
  __syncthreads();
  if (t < 256) {
    const int e4  = t << 2;
    const int row = e4 >> 6;
    const int col = e4 & 63;
    float s0 = 0.f, s1 = 0.f, s2 = 0.f, s3 = 0.f;
    #pragma unroll
    for (int wv = 0; wv < NW; wv++) {
      const float* p = ctxb + (size_t)(wv*16 + row)*66 + col;
      s0 += p[0]; s1 += p[1]; s2 += p[2]; s3 += p[3];
    }
    f32x4 o; o[0] = s0; o[1] = s1; o[2] = s2; o[3] = s3;
    *(f32x4*)(ctx_out + row*D_ + col) = o;
  }
}

extern "C" void kernel_launch(void* const* d_in, const int* in_sizes, int n_in,
                              void* d_out, int out_size, void* d_ws, size_t ws_size,
                              hipStream_t stream) {
  const float* Q = (const float*)d_in[0];
  const float* K = (const float*)d_in[1];
  const float* V = (const float*)d_in[2];
  const int* M = (const int*)d_in[3];
  float* out = (float*)d_out;
  sdpa_kernel<<<dim3(4096), dim3(512), 0, stream>>>(Q, K, V, M, out);
}